// Round 8
// baseline (16.687 us; speedup 1.0000x reference)
//
#include <hip/hip_runtime.h>

// Problem geometry (fixed by reference):
//   preds : (B=2, T=8, E=16, H=128, W=256) f32, idx ((b*8+t)*16+e)*HW + hw
//   target: (B=2, T=8, 1,    H=128, W=256) f32
//   output: scalar f32
//
// Regime note (R7 profile): the harness refills the ~268MB d_ws between
// replays, evicting all of L3 -> every replay streams preds/target from
// HBM. Memory-bound: floor = 35.6 MB / 6.3 TB/s ~= 5.7 us. So: vectorize
// (G13) and keep waves deep; keep the two-kernel structure (fused
// atomic tail = spill trigger, R5/R6).
#define HW    32768   // 128*256
#define HW2   16384   // HW/2 float2 groups
#define T_DIM 8
#define E_DIM 16
#define NPOS  65536   // B * HW
#define BLK   256
#define NTHREADS (2 * T_DIM * HW2)  // 262144: one thread per (b,t,hw2)
#define NBLK  (NTHREADS / BLK)      // 1024

__device__ __forceinline__ float block_reduce_256(float v, float* lds) {
#pragma unroll
    for (int off = 32; off; off >>= 1)
        v += __shfl_down(v, off, 64);
    int lane = threadIdx.x & 63;
    int wid  = threadIdx.x >> 6;
    if (lane == 0) lds[wid] = v;
    __syncthreads();
    return lds[0] + lds[1] + lds[2] + lds[3];
}

// One thread per (b, t, hw2-pair): 16 float2 loads (8B/lane, 64B contiguous
// per t-panel per wave-load). t in the low 3 lane bits -> temporal diff via
// __shfl(lane-1). Every element loaded exactly once. ~50 VGPR target.
__global__ __launch_bounds__(BLK) void crps_partial(const float* __restrict__ preds,
                                                    const float* __restrict__ target,
                                                    float* __restrict__ partials) {
    const int n  = blockIdx.x * BLK + threadIdx.x;   // 18 bits
    const int t  = n & 7;                            // lane bits [0,3)
    const int g  = (n >> 3) & (HW2 - 1);             // float2 group
    const int b  = n >> 17;

    const float2* pb = (const float2*)(preds + (size_t)((b * T_DIM + t) * E_DIM) * HW) + g;
    float2 cur[E_DIM];
#pragma unroll
    for (int e = 0; e < E_DIM; ++e)
        cur[e] = pb[(size_t)e * HW2];
    const float2 tgt = ((const float2*)(target + (size_t)(b * T_DIM + t) * HW))[g];

    // temporal transition (t-1 -> t): pull previous-t value from lane-1
    const int lane = threadIdx.x & 63;
    const int src  = (lane > 0) ? (lane - 1) : 0;
    float tacc = 0.f;
#pragma unroll
    for (int e = 0; e < E_DIM; ++e) {
        float pvx = __shfl(cur[e].x, src, 64);
        float pvy = __shfl(cur[e].y, src, 64);
        if (t > 0) {
            tacc += fabsf(cur[e].x - pvx);
            tacc += fabsf(cur[e].y - pvy);
        }
    }

    // term1: sum_e |p_e - tgt| (both hw components)
    float t1 = 0.f;
#pragma unroll
    for (int e = 0; e < E_DIM; ++e) {
        t1 += fabsf(cur[e].x - tgt.x);
        t1 += fabsf(cur[e].y - tgt.y);
    }
    // term2 core: sum_{i<j} |p_i - p_j|
    float s = 0.f;
#pragma unroll
    for (int i = 0; i < E_DIM; ++i)
#pragma unroll
        for (int j = i + 1; j < E_DIM; ++j) {
            s += fabsf(cur[i].x - cur[j].x);
            s += fabsf(cur[i].y - cur[j].y);
        }

    // contribution of the 2 (b,t,hw) elements this thread owns
    float v = (t1 * (1.f / 16.f) - s * (1.f / 256.f)) * (1.f / 8.f)
            + tacc * (0.1f / 112.f);

    __shared__ float lds[4];
    float bsum = block_reduce_256(v, lds);
    if (threadIdx.x == 0)
        partials[blockIdx.x] = bsum;
}

__global__ __launch_bounds__(BLK) void crps_final(const float* __restrict__ partials,
                                                  float* __restrict__ out) {
    float v = 0.f;
#pragma unroll
    for (int i = 0; i < NBLK / BLK; ++i)            // 4 partials per thread
        v += partials[i * BLK + threadIdx.x];
    __shared__ float lds[4];
    float total = block_reduce_256(v, lds);
    if (threadIdx.x == 0)
        out[0] = total * (1.f / (float)NPOS);
}

extern "C" void kernel_launch(void* const* d_in, const int* in_sizes, int n_in,
                              void* d_out, int out_size, void* d_ws, size_t ws_size,
                              hipStream_t stream) {
    const float* preds  = (const float*)d_in[0];
    const float* target = (const float*)d_in[1];
    float* out      = (float*)d_out;
    float* partials = (float*)d_ws;   // 1024 floats = 4 KB scratch

    crps_partial<<<NBLK, BLK, 0, stream>>>(preds, target, partials);
    crps_final<<<1, BLK, 0, stream>>>(partials, out);
}

// Round 9
// 13.988 us; speedup vs baseline: 1.1930x; 1.1930x over previous
//
#include <hip/hip_runtime.h>

// Problem geometry (fixed by reference):
//   preds : (B=2, T=8, E=16, H=128, W=256) f32, idx ((b*8+t)*16+e)*HW + hw
//   target: (B=2, T=8, 1,    H=128, W=256) f32
//   output: scalar f32
//
// Regime notes (R1-R8 evidence):
//  - Timed replays are L3-warm (harness doesn't re-poison between replays);
//    traffic cuts (R4) and load-instr cuts (R8) were both ~neutral -> the
//    partial kernel is VALU/latency-bound, not memory-bound.
//  - t-pair-per-thread, k in low 2 lane bits = best mapping (R4, 13.5us).
//    One-t mappings (R7/R8) +3us; LDS exchange (R3) +7us; fused atomic
//    tail (R5/R6) spills cur[] (VGPR 20-24) -> 3-5x. Keep two kernels.
//  - This round: cut term2 VALU 360->~142 ops/t via sort identity:
//    sum_{i<j}|xi-xj| = sum_j (2j-15) x_(j)  (Batcher-16, 63 CEs).
#define HW    32768   // 128*256
#define T_DIM 8
#define E_DIM 16
#define NPOS  65536   // B * HW
#define BLK   256
#define NTHREADS 262144                 // B * HW * 4 t-pairs
#define NBLK  (NTHREADS / BLK)          // 1024

__device__ __forceinline__ float block_reduce_256(float v, float* lds) {
#pragma unroll
    for (int off = 32; off; off >>= 1)
        v += __shfl_down(v, off, 64);
    int lane = threadIdx.x & 63;
    int wid  = threadIdx.x >> 6;
    if (lane == 0) lds[wid] = v;
    __syncthreads();
    return lds[0] + lds[1] + lds[2] + lds[3];
}

__device__ __forceinline__ void ce(float& a, float& b) {
    float lo = fminf(a, b);
    float hi = fmaxf(a, b);
    a = lo; b = hi;
}

// Sorts x[16] in place (Batcher odd-even mergesort, 63 comparators) and
// returns S = sum_{i<j} |x_i - x_j| = sum_j (2j-15) * x_sorted[j].
__device__ __forceinline__ float pairsum_destructive(float* x) {
    // p=1
    ce(x[0],x[1]);  ce(x[2],x[3]);  ce(x[4],x[5]);   ce(x[6],x[7]);
    ce(x[8],x[9]);  ce(x[10],x[11]); ce(x[12],x[13]); ce(x[14],x[15]);
    // p=2, k=2
    ce(x[0],x[2]);  ce(x[1],x[3]);  ce(x[4],x[6]);   ce(x[5],x[7]);
    ce(x[8],x[10]); ce(x[9],x[11]); ce(x[12],x[14]); ce(x[13],x[15]);
    // p=2, k=1
    ce(x[1],x[2]);  ce(x[5],x[6]);  ce(x[9],x[10]);  ce(x[13],x[14]);
    // p=4, k=4
    ce(x[0],x[4]);  ce(x[1],x[5]);  ce(x[2],x[6]);   ce(x[3],x[7]);
    ce(x[8],x[12]); ce(x[9],x[13]); ce(x[10],x[14]); ce(x[11],x[15]);
    // p=4, k=2
    ce(x[2],x[4]);  ce(x[3],x[5]);  ce(x[10],x[12]); ce(x[11],x[13]);
    // p=4, k=1
    ce(x[1],x[2]);  ce(x[3],x[4]);  ce(x[5],x[6]);
    ce(x[9],x[10]); ce(x[11],x[12]); ce(x[13],x[14]);
    // p=8, k=8
    ce(x[0],x[8]);  ce(x[1],x[9]);  ce(x[2],x[10]);  ce(x[3],x[11]);
    ce(x[4],x[12]); ce(x[5],x[13]); ce(x[6],x[14]);  ce(x[7],x[15]);
    // p=8, k=4
    ce(x[4],x[8]);  ce(x[5],x[9]);  ce(x[6],x[10]);  ce(x[7],x[11]);
    // p=8, k=2
    ce(x[2],x[4]);  ce(x[3],x[5]);  ce(x[6],x[8]);
    ce(x[7],x[9]);  ce(x[10],x[12]); ce(x[11],x[13]);
    // p=8, k=1
    ce(x[1],x[2]);  ce(x[3],x[4]);  ce(x[5],x[6]);   ce(x[7],x[8]);
    ce(x[9],x[10]); ce(x[11],x[12]); ce(x[13],x[14]);

    float s;
    s  = 15.f * (x[15] - x[0]);
    s += 13.f * (x[14] - x[1]);
    s += 11.f * (x[13] - x[2]);
    s +=  9.f * (x[12] - x[3]);
    s +=  7.f * (x[11] - x[4]);
    s +=  5.f * (x[10] - x[5]);
    s +=  3.f * (x[9]  - x[6]);
    s +=         x[8]  - x[7];
    return s;
}

// Thread (b, hw, k) owns t in {2k, 2k+1}; k lives in the low 2 lane bits so
// the thread holding pair k-1 (same hw) is lane-1 -> boundary temporal diffs
// via __shfl. Every preds/target element is loaded exactly once.
__global__ __launch_bounds__(BLK) void crps_partial(const float* __restrict__ preds,
                                                    const float* __restrict__ target,
                                                    float* __restrict__ partials) {
    const int n  = blockIdx.x * BLK + threadIdx.x;   // 18 bits
    const int k  = n & 3;                            // t-pair 0..3 (lane bits)
    const int hw = (n >> 2) & (HW - 1);              // 15 bits
    const int b  = n >> 17;                          // 0..1
    const int t0 = 2 * k;

    const float* pb = preds  + hw;
    const float* tb = target + hw;

    float cur0[E_DIM], cur1[E_DIM];
#pragma unroll
    for (int e = 0; e < E_DIM; ++e)
        cur0[e] = pb[((size_t)((b * T_DIM + t0) * E_DIM) + e) * HW];
#pragma unroll
    for (int e = 0; e < E_DIM; ++e)
        cur1[e] = pb[((size_t)((b * T_DIM + t0 + 1) * E_DIM) + e) * HW];
    const float tgt0 = tb[(size_t)(b * T_DIM + t0) * HW];
    const float tgt1 = tb[(size_t)(b * T_DIM + t0 + 1) * HW];

    // boundary transition t=2k-1 -> 2k: pull neighbor lane's cur1 (original order!)
    const int lane = threadIdx.x & 63;
    const int src  = (lane > 0) ? (lane - 1) : 0;
    float tacc = 0.f;
#pragma unroll
    for (int e = 0; e < E_DIM; ++e) {
        float pv = __shfl(cur1[e], src, 64);         // exec-sync, DS pipe
        if (k > 0)
            tacc += fabsf(cur0[e] - pv);
    }
    // within-pair transition t=2k -> 2k+1 (original order)
#pragma unroll
    for (int e = 0; e < E_DIM; ++e)
        tacc += fabsf(cur1[e] - cur0[e]);

    // term1 (original order)
    float t1 = 0.f;
#pragma unroll
    for (int e = 0; e < E_DIM; ++e)
        t1 += fabsf(cur0[e] - tgt0) + fabsf(cur1[e] - tgt1);

    // term2 via sort identity — clobbers cur0/cur1 (no longer needed)
    float s0 = pairsum_destructive(cur0);
    float s1 = pairsum_destructive(cur1);

    float acc = t1 * (1.f / 16.f) - (s0 + s1) * (1.f / 256.f);

    // per-(b,hw) scaling: crps terms averaged over 8 t; temporal over 112
    float v = acc * (1.f / 8.f) + tacc * (0.1f / 112.f);

    __shared__ float lds[4];
    float bsum = block_reduce_256(v, lds);
    if (threadIdx.x == 0)
        partials[blockIdx.x] = bsum;
}

__global__ __launch_bounds__(BLK) void crps_final(const float* __restrict__ partials,
                                                  float* __restrict__ out) {
    float v = 0.f;
#pragma unroll
    for (int i = 0; i < NBLK / BLK; ++i)            // 4 partials per thread
        v += partials[i * BLK + threadIdx.x];
    __shared__ float lds[4];
    float total = block_reduce_256(v, lds);
    if (threadIdx.x == 0)
        out[0] = total * (1.f / (float)NPOS);
}

extern "C" void kernel_launch(void* const* d_in, const int* in_sizes, int n_in,
                              void* d_out, int out_size, void* d_ws, size_t ws_size,
                              hipStream_t stream) {
    const float* preds  = (const float*)d_in[0];
    const float* target = (const float*)d_in[1];
    float* out      = (float*)d_out;
    float* partials = (float*)d_ws;   // 1024 floats = 4 KB scratch

    crps_partial<<<NBLK, BLK, 0, stream>>>(preds, target, partials);
    crps_final<<<1, BLK, 0, stream>>>(partials, out);
}